// Round 7
// baseline (395.695 us; speedup 1.0000x reference)
//
#include <hip/hip_runtime.h>
#include <math.h>

// Problem constants (fixed by the reference file)
constexpr int B = 256;
constexpr int L = 1024;
constexpr int D = 512;
constexpr int DV = D / 4;                         // 128 float4 per row
constexpr float INV_T = 0.044194173824159216f;    // 1/sqrt(512)

typedef float f4nt __attribute__((ext_vector_type(4)));
__device__ __forceinline__ void nt_store4(float4* p, float4 val) {
    __builtin_nontemporal_store(*reinterpret_cast<f4nt*>(&val),
                                reinterpret_cast<f4nt*>(p));
}

// ============ K1: logits = q.kc / T ; gates = sigmoid(q.kd / T) ============
// grid = B*8 blocks, 256 threads. Block (b, rchunk) handles 128 rows.
__global__ __launch_bounds__(256) void cda_k1_logits(
    const float* __restrict__ q,
    const float* __restrict__ kc,
    const float* __restrict__ kd,
    float* __restrict__ logits,   // (B,L) in d_out tail
    float* __restrict__ gates)    // (B,L) in ws
{
    const int b      = blockIdx.x >> 3;
    const int rchunk = blockIdx.x & 7;
    const int l0     = rchunk * 128;
    const int tid    = threadIdx.x;
    const int t16    = tid & 15;
    const int grp    = tid >> 4;          // 0..15 row-groups

    __shared__ float s_log[128];
    __shared__ float s_gate[128];

    const float4* q4 = reinterpret_cast<const float4*>(q + (size_t)b * D);
    float4 qr[8];
    #pragma unroll
    for (int k = 0; k < 8; ++k) qr[k] = q4[t16 + k * 16];

    const float4* kc4 = reinterpret_cast<const float4*>(kc + (size_t)b * L * D);
    const float4* kd4 = reinterpret_cast<const float4*>(kd + (size_t)b * L * D);

    #pragma unroll 2
    for (int it = 0; it < 8; ++it) {
        const int lr = it * 16 + grp;     // row within chunk
        const int l  = l0 + lr;
        const float4* rowc = kc4 + (size_t)l * DV + t16;
        const float4* rowd = kd4 + (size_t)l * DV + t16;
        float dc = 0.f, dd = 0.f;
        #pragma unroll
        for (int k = 0; k < 8; ++k) {
            const float4 c = rowc[k * 16];
            const float4 e = rowd[k * 16];
            dc += qr[k].x * c.x + qr[k].y * c.y + qr[k].z * c.z + qr[k].w * c.w;
            dd += qr[k].x * e.x + qr[k].y * e.y + qr[k].z * e.z + qr[k].w * e.w;
        }
        dc += __shfl_xor(dc, 8); dd += __shfl_xor(dd, 8);
        dc += __shfl_xor(dc, 4); dd += __shfl_xor(dd, 4);
        dc += __shfl_xor(dc, 2); dd += __shfl_xor(dd, 2);
        dc += __shfl_xor(dc, 1); dd += __shfl_xor(dd, 1);
        if (t16 == 0) {
            s_log[lr]  = dc * INV_T;
            s_gate[lr] = 1.0f / (1.0f + __expf(-dd * INV_T));
        }
    }
    __syncthreads();

    if (tid < 128) {
        logits[(size_t)b * L + l0 + tid] = s_log[tid];
        gates [(size_t)b * L + l0 + tid] = s_gate[tid];
    }
}

// ====== K23: softmax + column-slice v-reduction + direct output write ======
// grid = B*8 blocks, 256 threads. Block (b, cg) owns float4 columns
// [cg*16, cg*16+16) (= 64 floats). Reads all L logits+gates (8 KB),
// streams v[:, slice] (256 KB), writes out[:, slice] (256 KB, NT).
// No cross-block dependencies.
__global__ __launch_bounds__(256) void cda_k23(
    const float* __restrict__ logits,
    const float* __restrict__ gates,
    const float* __restrict__ v,
    float* __restrict__ out)
{
    const int b    = blockIdx.x >> 3;
    const int cg   = blockIdx.x & 7;
    const int tid  = threadIdx.x;
    const int lane = tid & 63;
    const int wave = tid >> 6;        // 0..3

    __shared__ float  s_w[L];             // 4 KB softmax weights
    __shared__ float  s_gate[L];          // 4 KB gates
    __shared__ float4 s_acc[16][16];      // 4 KB partial column accumulators
    __shared__ float4 s_attn[16];         // my 16 float4 of attn
    __shared__ float  s_red[4];
    __shared__ float  s_red2[4];

    // ---- load logits + gates (float4 each), softmax over L (redundant) ----
    const float4 lg = reinterpret_cast<const float4*>(logits + (size_t)b * L)[tid];
    const float4 gt = reinterpret_cast<const float4*>(gates  + (size_t)b * L)[tid];
    reinterpret_cast<float4*>(s_gate)[tid] = gt;

    float m = fmaxf(fmaxf(lg.x, lg.y), fmaxf(lg.z, lg.w));
    #pragma unroll
    for (int off = 32; off; off >>= 1) m = fmaxf(m, __shfl_xor(m, off));
    if (lane == 0) s_red[wave] = m;
    __syncthreads();
    float gm = fmaxf(fmaxf(s_red[0], s_red[1]), fmaxf(s_red[2], s_red[3]));

    float4 e;
    e.x = __expf(lg.x - gm);
    e.y = __expf(lg.y - gm);
    e.z = __expf(lg.z - gm);
    e.w = __expf(lg.w - gm);
    float ssum = (e.x + e.y) + (e.z + e.w);
    #pragma unroll
    for (int off = 32; off; off >>= 1) ssum += __shfl_xor(ssum, off);
    if (lane == 0) s_red2[wave] = ssum;
    __syncthreads();
    const float gs = (s_red2[0] + s_red2[1]) + (s_red2[2] + s_red2[3]);
    const float rgs = 1.0f / gs;

    reinterpret_cast<float4*>(s_w)[tid] =
        make_float4(e.x * rgs, e.y * rgs, e.z * rgs, e.w * rgs);
    __syncthreads();

    // ---- v-reduction over my column slice: attn[c] = sum_l w[l] v[l,c] ----
    const float4* v4 = reinterpret_cast<const float4*>(v + (size_t)b * L * D)
                       + cg * 16;
    const int c = tid & 15;           // float4 column within slice
    const int g = tid >> 4;           // row group 0..15 (64 rows each)
    float4 acc0 = make_float4(0.f, 0.f, 0.f, 0.f);
    float4 acc1 = make_float4(0.f, 0.f, 0.f, 0.f);
    #pragma unroll 4
    for (int it = 0; it < 64; it += 2) {
        const int l0 = it * 16 + g;
        const int l1 = l0 + 16;
        const float w0 = s_w[l0];
        const float w1 = s_w[l1];
        const float4 va = v4[(size_t)l0 * DV + c];
        const float4 vb = v4[(size_t)l1 * DV + c];
        acc0.x += w0 * va.x; acc0.y += w0 * va.y;
        acc0.z += w0 * va.z; acc0.w += w0 * va.w;
        acc1.x += w1 * vb.x; acc1.y += w1 * vb.y;
        acc1.z += w1 * vb.z; acc1.w += w1 * vb.w;
    }
    acc0.x += acc1.x; acc0.y += acc1.y; acc0.z += acc1.z; acc0.w += acc1.w;
    s_acc[g][c] = acc0;
    __syncthreads();

    if (tid < 16) {
        float4 a = s_acc[0][tid];
        #pragma unroll
        for (int gg = 1; gg < 16; ++gg) {
            const float4 p = s_acc[gg][tid];
            a.x += p.x; a.y += p.y; a.z += p.z; a.w += p.w;
        }
        s_attn[tid] = a;
    }
    __syncthreads();

    // ---- write out[l, slice] = gate[l] * attn for all l (NT streaming) ----
    float4* out4 = reinterpret_cast<float4*>(out + (size_t)b * L * D) + cg * 16;
    #pragma unroll 4
    for (int i = tid; i < L * 16; i += 256) {
        const int l  = i >> 4;
        const int cc = i & 15;
        const float sg = s_gate[l];
        const float4 a = s_attn[cc];
        nt_store4(&out4[(size_t)l * DV + cc],
                  make_float4(sg * a.x, sg * a.y, sg * a.z, sg * a.w));
    }
}

extern "C" void kernel_launch(void* const* d_in, const int* in_sizes, int n_in,
                              void* d_out, int out_size, void* d_ws, size_t ws_size,
                              hipStream_t stream) {
    const float* q  = (const float*)d_in[0];
    const float* kc = (const float*)d_in[1];
    const float* kd = (const float*)d_in[2];
    const float* v  = (const float*)d_in[3];
    float* out    = (float*)d_out;                       // (B,L,D) flat
    float* logits = out + (size_t)B * L * D;             // (B,L) flat

    float* gates = (float*)d_ws;                         // B*L floats = 1 MB

    hipLaunchKernelGGL(cda_k1_logits, dim3(B * 8), dim3(256), 0, stream,
                       q, kc, kd, logits, gates);
    hipLaunchKernelGGL(cda_k23, dim3(B * 8), dim3(256), 0, stream,
                       logits, gates, v, out);
}

// Round 8
// 373.618 us; speedup vs baseline: 1.0591x; 1.0591x over previous
//
#include <hip/hip_runtime.h>
#include <math.h>

// Problem constants (fixed by the reference file)
constexpr int B = 256;
constexpr int L = 1024;
constexpr int D = 512;
constexpr int DV = D / 4;                         // 128 float4 per row
constexpr float INV_T = 0.044194173824159216f;    // 1/sqrt(512)

typedef float f4nt __attribute__((ext_vector_type(4)));
__device__ __forceinline__ void nt_store4(float4* p, float4 val) {
    __builtin_nontemporal_store(*reinterpret_cast<f4nt*>(&val),
                                reinterpret_cast<f4nt*>(p));
}

// ============ K1: logits = q.kc / T ; gates = sigmoid(q.kd / T) ============
// grid = B*8 blocks, 256 threads. Block (b, rchunk) handles 128 rows.
// Whole-wave-per-row: each row of kc (and kd) is read as 2 x 1KB contiguous
// wave bursts; the block's 4 waves sweep an 8-row (16KB) sequential front.
__global__ __launch_bounds__(256) void cda_k1_logits(
    const float* __restrict__ q,
    const float* __restrict__ kc,
    const float* __restrict__ kd,
    float* __restrict__ logits,   // (B,L) in d_out tail
    float* __restrict__ gates)    // (B,L) in ws
{
    const int b      = blockIdx.x >> 3;
    const int rchunk = blockIdx.x & 7;
    const int l0     = rchunk * 128;
    const int tid    = threadIdx.x;
    const int lane   = tid & 63;
    const int wave   = tid >> 6;          // 0..3

    __shared__ float s_log[128];
    __shared__ float s_gate[128];

    const float4* q4 = reinterpret_cast<const float4*>(q + (size_t)b * D);
    const float4 qa = q4[lane];           // float cols [4*lane, 4*lane+4)
    const float4 qb = q4[lane + 64];      // float cols [256+4*lane, ...)

    const float4* kc4 = reinterpret_cast<const float4*>(kc) + ((size_t)b * L + l0) * DV;
    const float4* kd4 = reinterpret_cast<const float4*>(kd) + ((size_t)b * L + l0) * DV;

    // iteration it: waves cover rows [it*8, it*8+8); wave w owns rows it*8+2w, +1
    #pragma unroll 2
    for (int it = 0; it < 16; ++it) {
        const int la = it * 8 + wave * 2;
        const int lb = la + 1;
        const float4 ca0 = kc4[(size_t)la * DV + lane];
        const float4 ca1 = kc4[(size_t)la * DV + 64 + lane];
        const float4 cb0 = kc4[(size_t)lb * DV + lane];
        const float4 cb1 = kc4[(size_t)lb * DV + 64 + lane];
        const float4 da0 = kd4[(size_t)la * DV + lane];
        const float4 da1 = kd4[(size_t)la * DV + 64 + lane];
        const float4 db0 = kd4[(size_t)lb * DV + lane];
        const float4 db1 = kd4[(size_t)lb * DV + 64 + lane];

        float dc0 = qa.x * ca0.x + qa.y * ca0.y + qa.z * ca0.z + qa.w * ca0.w
                  + qb.x * ca1.x + qb.y * ca1.y + qb.z * ca1.z + qb.w * ca1.w;
        float dc1 = qa.x * cb0.x + qa.y * cb0.y + qa.z * cb0.z + qa.w * cb0.w
                  + qb.x * cb1.x + qb.y * cb1.y + qb.z * cb1.z + qb.w * cb1.w;
        float dd0 = qa.x * da0.x + qa.y * da0.y + qa.z * da0.z + qa.w * da0.w
                  + qb.x * da1.x + qb.y * da1.y + qb.z * da1.z + qb.w * da1.w;
        float dd1 = qa.x * db0.x + qa.y * db0.y + qa.z * db0.z + qa.w * db0.w
                  + qb.x * db1.x + qb.y * db1.y + qb.z * db1.z + qb.w * db1.w;

        #pragma unroll
        for (int off = 32; off; off >>= 1) {
            dc0 += __shfl_xor(dc0, off);
            dc1 += __shfl_xor(dc1, off);
            dd0 += __shfl_xor(dd0, off);
            dd1 += __shfl_xor(dd1, off);
        }
        if (lane == 0) {
            s_log[la]  = dc0 * INV_T;
            s_log[lb]  = dc1 * INV_T;
            s_gate[la] = 1.0f / (1.0f + __expf(-dd0 * INV_T));
            s_gate[lb] = 1.0f / (1.0f + __expf(-dd1 * INV_T));
        }
    }
    __syncthreads();

    if (tid < 128) {
        logits[(size_t)b * L + l0 + tid] = s_log[tid];
        gates [(size_t)b * L + l0 + tid] = s_gate[tid];
    }
}

// ====== K23: softmax + column-slice v-reduction + direct output write ======
// grid = B*2 blocks, 512 threads. Block (b, cg) owns float4 columns
// [cg*64, cg*64+64) = a 1KB-per-row slice. Reads all L logits+gates (8 KB),
// streams v[:, slice] (1KB-per-wave bursts, 8-wave sequential front),
// writes out[:, slice] with 1KB-per-wave NT bursts.
__global__ __launch_bounds__(512) void cda_k23(
    const float* __restrict__ logits,
    const float* __restrict__ gates,
    const float* __restrict__ v,
    float* __restrict__ out)
{
    const int b    = blockIdx.x >> 1;
    const int cg   = blockIdx.x & 1;
    const int tid  = threadIdx.x;
    const int lane = tid & 63;
    const int wave = tid >> 6;        // 0..7

    __shared__ float  s_w[L];             // 4 KB softmax weights
    __shared__ float  s_gate[L];          // 4 KB gates
    __shared__ float4 s_acc[8][64];       // 8 KB partial column accumulators
    __shared__ float4 s_attn[64];         // my 64 float4 of attn
    __shared__ float  s_red[8];
    __shared__ float  s_red2[8];

    // ---- load logits + gates, softmax over L (redundant per cg - free) ----
    const float x0 = logits[(size_t)b * L + tid];
    const float x1 = logits[(size_t)b * L + tid + 512];
    s_gate[tid]       = gates[(size_t)b * L + tid];
    s_gate[tid + 512] = gates[(size_t)b * L + tid + 512];

    float m = fmaxf(x0, x1);
    #pragma unroll
    for (int off = 32; off; off >>= 1) m = fmaxf(m, __shfl_xor(m, off));
    if (lane == 0) s_red[wave] = m;
    __syncthreads();
    float gm = s_red[0];
    #pragma unroll
    for (int i = 1; i < 8; ++i) gm = fmaxf(gm, s_red[i]);

    const float e0 = __expf(x0 - gm);
    const float e1 = __expf(x1 - gm);
    float ssum = e0 + e1;
    #pragma unroll
    for (int off = 32; off; off >>= 1) ssum += __shfl_xor(ssum, off);
    if (lane == 0) s_red2[wave] = ssum;
    __syncthreads();
    float gs = 0.0f;
    #pragma unroll
    for (int i = 0; i < 8; ++i) gs += s_red2[i];
    const float rgs = 1.0f / gs;

    s_w[tid]       = e0 * rgs;
    s_w[tid + 512] = e1 * rgs;
    __syncthreads();

    // ---- v-reduction over my 1KB column slice ----
    // iteration r: 8 waves cover rows [r*8, r*8+8) (16KB sequential front);
    // wave g reads row r*8+g as one 1KB contiguous burst.
    const float4* v4 = reinterpret_cast<const float4*>(v + (size_t)b * L * D)
                       + cg * 64;
    float4 acc0 = make_float4(0.f, 0.f, 0.f, 0.f);
    float4 acc1 = make_float4(0.f, 0.f, 0.f, 0.f);
    #pragma unroll 4
    for (int r = 0; r < 128; r += 2) {
        const int l0 = (r)     * 8 + wave;
        const int l1 = (r + 1) * 8 + wave;
        const float w0 = s_w[l0];
        const float w1 = s_w[l1];
        const float4 va = v4[(size_t)l0 * DV + lane];
        const float4 vb = v4[(size_t)l1 * DV + lane];
        acc0.x += w0 * va.x; acc0.y += w0 * va.y;
        acc0.z += w0 * va.z; acc0.w += w0 * va.w;
        acc1.x += w1 * vb.x; acc1.y += w1 * vb.y;
        acc1.z += w1 * vb.z; acc1.w += w1 * vb.w;
    }
    acc0.x += acc1.x; acc0.y += acc1.y; acc0.z += acc1.z; acc0.w += acc1.w;
    s_acc[wave][lane] = acc0;
    __syncthreads();

    if (tid < 64) {
        float4 a = s_acc[0][tid];
        #pragma unroll
        for (int gg = 1; gg < 8; ++gg) {
            const float4 p = s_acc[gg][tid];
            a.x += p.x; a.y += p.y; a.z += p.z; a.w += p.w;
        }
        s_attn[tid] = a;
    }
    __syncthreads();

    // ---- write out[l, slice] = gate[l] * attn (1KB-per-wave NT bursts) ----
    float4* out4 = reinterpret_cast<float4*>(out + (size_t)b * L * D) + cg * 64;
    #pragma unroll 4
    for (int i = tid; i < L * 64; i += 512) {
        const int l  = i >> 6;
        const int cc = i & 63;
        const float sg = s_gate[l];
        const float4 a = s_attn[cc];
        nt_store4(&out4[(size_t)l * DV + cc],
                  make_float4(sg * a.x, sg * a.y, sg * a.z, sg * a.w));
    }
}

extern "C" void kernel_launch(void* const* d_in, const int* in_sizes, int n_in,
                              void* d_out, int out_size, void* d_ws, size_t ws_size,
                              hipStream_t stream) {
    const float* q  = (const float*)d_in[0];
    const float* kc = (const float*)d_in[1];
    const float* kd = (const float*)d_in[2];
    const float* v  = (const float*)d_in[3];
    float* out    = (float*)d_out;                       // (B,L,D) flat
    float* logits = out + (size_t)B * L * D;             // (B,L) flat

    float* gates = (float*)d_ws;                         // B*L floats = 1 MB

    hipLaunchKernelGGL(cda_k1_logits, dim3(B * 8), dim3(256), 0, stream,
                       q, kc, kd, logits, gates);
    hipLaunchKernelGGL(cda_k23, dim3(B * 2), dim3(512), 0, stream,
                       logits, gates, v, out);
}

// Round 9
// 368.462 us; speedup vs baseline: 1.0739x; 1.0140x over previous
//
#include <hip/hip_runtime.h>
#include <math.h>

// Problem constants (fixed by the reference file)
constexpr int B = 256;
constexpr int L = 1024;
constexpr int D = 512;
constexpr int DV = D / 4;                         // 128 float4 per row
constexpr float INV_T = 0.044194173824159216f;    // 1/sqrt(512)

typedef float f4nt __attribute__((ext_vector_type(4)));
__device__ __forceinline__ void nt_store4(float4* p, float4 val) {
    __builtin_nontemporal_store(*reinterpret_cast<f4nt*>(&val),
                                reinterpret_cast<f4nt*>(p));
}

// ============ K1: logits = q.kc / T ; gates = sigmoid(q.kd / T) ============
// grid = B*8 blocks, 256 threads. Block (b, rchunk) handles 128 rows.
// 16-lane row-groups, 256B granules: measured optimum (r6=369 vs r7/256B=396,
// r8/1KB=374 us).
__global__ __launch_bounds__(256) void cda_k1_logits(
    const float* __restrict__ q,
    const float* __restrict__ kc,
    const float* __restrict__ kd,
    float* __restrict__ logits,   // (B,L) in d_out tail
    float* __restrict__ gates)    // (B,L) in ws
{
    const int b      = blockIdx.x >> 3;
    const int rchunk = blockIdx.x & 7;
    const int l0     = rchunk * 128;
    const int tid    = threadIdx.x;
    const int t16    = tid & 15;
    const int grp    = tid >> 4;          // 0..15 row-groups

    __shared__ float s_log[128];
    __shared__ float s_gate[128];

    const float4* q4 = reinterpret_cast<const float4*>(q + (size_t)b * D);
    float4 qr[8];
    #pragma unroll
    for (int k = 0; k < 8; ++k) qr[k] = q4[t16 + k * 16];

    const float4* kc4 = reinterpret_cast<const float4*>(kc + (size_t)b * L * D);
    const float4* kd4 = reinterpret_cast<const float4*>(kd + (size_t)b * L * D);

    #pragma unroll 2
    for (int it = 0; it < 8; ++it) {
        const int lr = it * 16 + grp;     // row within chunk
        const int l  = l0 + lr;
        const float4* rowc = kc4 + (size_t)l * DV + t16;
        const float4* rowd = kd4 + (size_t)l * DV + t16;
        float dc = 0.f, dd = 0.f;
        #pragma unroll
        for (int k = 0; k < 8; ++k) {
            const float4 c = rowc[k * 16];
            const float4 e = rowd[k * 16];
            dc += qr[k].x * c.x + qr[k].y * c.y + qr[k].z * c.z + qr[k].w * c.w;
            dd += qr[k].x * e.x + qr[k].y * e.y + qr[k].z * e.z + qr[k].w * e.w;
        }
        dc += __shfl_xor(dc, 8); dd += __shfl_xor(dd, 8);
        dc += __shfl_xor(dc, 4); dd += __shfl_xor(dd, 4);
        dc += __shfl_xor(dc, 2); dd += __shfl_xor(dd, 2);
        dc += __shfl_xor(dc, 1); dd += __shfl_xor(dd, 1);
        if (t16 == 0) {
            s_log[lr]  = dc * INV_T;
            s_gate[lr] = 1.0f / (1.0f + __expf(-dd * INV_T));
        }
    }
    __syncthreads();

    if (tid < 128) {
        logits[(size_t)b * L + l0 + tid] = s_log[tid];
        gates [(size_t)b * L + l0 + tid] = s_gate[tid];
    }
}

// ====== K23: softmax + column-slice v-reduction + direct output write ======
// grid = B*4 blocks, 512 threads. Block (b, cg) owns float columns
// [cg*128, cg*128+128) = float4 cols [cg*32, cg*32+32) — 512B per row.
// Reads all L logits+gates (8 KB), streams v[:, slice] (512 KB),
// writes out[:, slice] (512 KB) with NT stores. No cross-block deps.
__global__ __launch_bounds__(512) void cda_k23(
    const float* __restrict__ logits,
    const float* __restrict__ gates,
    const float* __restrict__ v,
    float* __restrict__ out)
{
    const int b    = blockIdx.x >> 2;
    const int cg   = blockIdx.x & 3;
    const int tid  = threadIdx.x;
    const int lane = tid & 63;
    const int wave = tid >> 6;        // 0..7

    __shared__ float  s_w[L];             // 4 KB softmax weights
    __shared__ float  s_gate[L];          // 4 KB gates
    __shared__ float4 s_acc[16][32];      // 8 KB partial column accumulators
    __shared__ float4 s_attn[32];         // my 32 float4 of attn
    __shared__ float  s_red[8];
    __shared__ float  s_red2[8];

    // ---- load logits + gates, softmax over L (redundant per cg - free) ----
    const float x0 = logits[(size_t)b * L + tid];
    const float x1 = logits[(size_t)b * L + tid + 512];
    s_gate[tid]       = gates[(size_t)b * L + tid];
    s_gate[tid + 512] = gates[(size_t)b * L + tid + 512];

    float m = fmaxf(x0, x1);
    #pragma unroll
    for (int off = 32; off; off >>= 1) m = fmaxf(m, __shfl_xor(m, off));
    if (lane == 0) s_red[wave] = m;
    __syncthreads();
    float gm = s_red[0];
    #pragma unroll
    for (int i = 1; i < 8; ++i) gm = fmaxf(gm, s_red[i]);

    const float e0 = __expf(x0 - gm);
    const float e1 = __expf(x1 - gm);
    float ssum = e0 + e1;
    #pragma unroll
    for (int off = 32; off; off >>= 1) ssum += __shfl_xor(ssum, off);
    if (lane == 0) s_red2[wave] = ssum;
    __syncthreads();
    float gs = 0.0f;
    #pragma unroll
    for (int i = 0; i < 8; ++i) gs += s_red2[i];
    const float rgs = 1.0f / gs;

    s_w[tid]       = e0 * rgs;
    s_w[tid + 512] = e1 * rgs;
    __syncthreads();

    // ---- v-reduction over my column slice: attn[c] = sum_l w[l] v[l,c] ----
    const float4* v4 = reinterpret_cast<const float4*>(v + (size_t)b * L * D)
                       + cg * 32;
    const int c = tid & 31;           // float4 column within slice
    const int g = tid >> 5;           // row group 0..15
    float4 acc0 = make_float4(0.f, 0.f, 0.f, 0.f);
    float4 acc1 = make_float4(0.f, 0.f, 0.f, 0.f);
    #pragma unroll 4
    for (int it = 0; it < 64; it += 2) {
        const int l0 = it * 16 + g;
        const int l1 = l0 + 16;
        const float w0 = s_w[l0];
        const float w1 = s_w[l1];
        const float4 va = v4[(size_t)l0 * DV + c];
        const float4 vb = v4[(size_t)l1 * DV + c];
        acc0.x += w0 * va.x; acc0.y += w0 * va.y;
        acc0.z += w0 * va.z; acc0.w += w0 * va.w;
        acc1.x += w1 * vb.x; acc1.y += w1 * vb.y;
        acc1.z += w1 * vb.z; acc1.w += w1 * vb.w;
    }
    acc0.x += acc1.x; acc0.y += acc1.y; acc0.z += acc1.z; acc0.w += acc1.w;
    s_acc[g][c] = acc0;
    __syncthreads();

    if (tid < 32) {
        float4 a = s_acc[0][tid];
        #pragma unroll
        for (int gg = 1; gg < 16; ++gg) {
            const float4 p = s_acc[gg][tid];
            a.x += p.x; a.y += p.y; a.z += p.z; a.w += p.w;
        }
        s_attn[tid] = a;
    }
    __syncthreads();

    // ---- write out[l, slice] = gate[l] * attn for all l (NT streaming) ----
    float4* out4 = reinterpret_cast<float4*>(out + (size_t)b * L * D) + cg * 32;
    #pragma unroll 4
    for (int i = tid; i < L * 32; i += 512) {
        const int l  = i >> 5;
        const int cc = i & 31;
        const float sg = s_gate[l];
        const float4 a = s_attn[cc];
        nt_store4(&out4[(size_t)l * DV + cc],
                  make_float4(sg * a.x, sg * a.y, sg * a.z, sg * a.w));
    }
}

extern "C" void kernel_launch(void* const* d_in, const int* in_sizes, int n_in,
                              void* d_out, int out_size, void* d_ws, size_t ws_size,
                              hipStream_t stream) {
    const float* q  = (const float*)d_in[0];
    const float* kc = (const float*)d_in[1];
    const float* kd = (const float*)d_in[2];
    const float* v  = (const float*)d_in[3];
    float* out    = (float*)d_out;                       // (B,L,D) flat
    float* logits = out + (size_t)B * L * D;             // (B,L) flat

    float* gates = (float*)d_ws;                         // B*L floats = 1 MB

    hipLaunchKernelGGL(cda_k1_logits, dim3(B * 8), dim3(256), 0, stream,
                       q, kc, kd, logits, gates);
    hipLaunchKernelGGL(cda_k23, dim3(B * 4), dim3(512), 0, stream,
                       logits, gates, v, out);
}